// Round 5
// baseline (129.208 us; speedup 1.0000x reference)
//
#include <hip/hip_runtime.h>
#include <hip/hip_bf16.h>

// ---------------------------------------------------------------------------
// Compile-time Clifford algebra tables (N_GEN=6, DIM=64), replicating the
// reference _build_algebra() exactly: blades sorted by (popcount, value).
// ---------------------------------------------------------------------------
namespace alg {
constexpr int pc(int v) { int c = 0; while (v) { c += v & 1; v >>= 1; } return c; }
constexpr int swap_sign_i(int a, int b) {
  int s = 0; a >>= 1;
  while (a) { s += pc(a & b); a >>= 1; }
  return (s & 1) ? -1 : 1;
}
struct Tables {
  int blade[64]; int index[64]; int cls[64];
  int itab[64][64]; int sgn[64][64]; int ct[64][64];
  constexpr Tables() : blade{}, index{}, cls{}, itab{}, sgn{}, ct{} {
    int pos = 0;
    for (int g = 0; g <= 6; ++g)
      for (int b = 0; b < 64; ++b)
        if (pc(b) == g) { blade[pos] = b; index[b] = pos; ++pos; }
    for (int i = 0; i < 64; ++i) cls[i] = pc(blade[i]) & 3;
    for (int J = 0; J < 64; ++J)
      for (int K = 0; K < 64; ++K) {
        int bj = blade[J], bk = blade[K], bi = bj ^ bk;
        int I = index[bi];
        itab[J][K] = I;
        sgn[J][K] = swap_sign_i(bi, bk);
        ct[J][K] = cls[I] * 16 + cls[J] * 4 + cls[K];
      }
  }
};
constexpr Tables T{};
}  // namespace alg

__device__ __forceinline__ float rfl(float v) {
  return __uint_as_float(__builtin_amdgcn_readfirstlane(__float_as_uint(v)));
}

// ---------------------------------------------------------------------------
// Kernel 1 (prep): blocks 0..511  : transpose x[b][m][i] -> xT[i][m][b]
//                  blocks 512..767: Wt[c][m][n] = w_lin[n][m][c]
//                  blocks 768..799: g[n][ci*16+cj*4+ck] from w_gp/path_idx
// ---------------------------------------------------------------------------
__global__ __launch_bounds__(256) void kprep(
    const float* __restrict__ x, const float* __restrict__ wlin,
    const float* __restrict__ wgp, const int* __restrict__ pidx, int P,
    float* __restrict__ xT, float* __restrict__ Wt, float* __restrict__ g) {
  int bid = blockIdx.x;
  if (bid < 512) {
    __shared__ float tile[64 * 65];
    int m = bid >> 2, bc = (bid & 3) << 6;
    int lane = threadIdx.x & 63, row = threadIdx.x >> 6;
#pragma unroll
    for (int p = 0; p < 16; ++p) {
      int b = p * 4 + row;
      tile[lane * 65 + b] = x[(bc + b) * 8192 + m * 64 + lane];
    }
    __syncthreads();
#pragma unroll
    for (int p = 0; p < 16; ++p) {
      int il = p * 4 + row;
      xT[il * 32768 + m * 256 + bc + lane] = tile[il * 65 + lane];
    }
  } else if (bid < 768) {
    int id = (bid - 512) * 256 + threadIdx.x;  // 0..65535
    int n = id & 127, m = (id >> 7) & 127, c = id >> 14;
    Wt[c * 16384 + m * 128 + n] = wlin[n * 512 + m * 4 + c];
  } else {
    int id = (bid - 768) * 256 + threadIdx.x;  // 0..8191
    int n = id >> 6, t = id & 63;
    int ti = t >> 4, tj = (t >> 2) & 3, tk = t & 3;
    float v = 0.f;
    for (int p = 0; p < P; ++p)
      if (pidx[p * 3] == ti && pidx[p * 3 + 1] == tj && pidx[p * 3 + 2] == tk)
        v = wgp[n * P + p];
    g[n * 64 + t] = v;
  }
}

// ---------------------------------------------------------------------------
// Kernel 2 (linear): xr[b,n,i] = sum_m x[b,m,i]*Wt[cls_i][m][n]  (+b_lin at i=0)
// Block = (i, bc), 512 threads = 8 waves. The block's xT slice [i][all m][64 b]
// (32 KB) is staged in LDS ONCE. Wave w computes n-tile [16w, 16w+16);
// lane = b. Weights via float4 from L2 (4 x 64-KB pages, L2-hot).
// ---------------------------------------------------------------------------
__global__ __launch_bounds__(512) void klin(
    const float* __restrict__ xT, const float* __restrict__ Wt,
    const float* __restrict__ blin, float* __restrict__ xrT) {
  __shared__ float xs[128 * 64];  // [m][b], 32 KB
  int bid = blockIdx.x;           // 256 blocks: (i in 0..63) x (bc in 0..3)
  int i = bid >> 2;
  int bc = (bid & 3) << 6;
  int ci = alg::T.cls[i];
  int t = threadIdx.x;
  {
    int b = t & 63, m0 = t >> 6;  // m0 in 0..7
    const float* src = xT + i * 32768 + bc + b;
#pragma unroll
    for (int r = 0; r < 16; ++r) {
      int m = m0 * 16 + r;
      xs[m * 64 + b] = src[m * 256];
    }
  }
  __syncthreads();

  int w = t >> 6;       // wave 0..7 -> n-tile
  int lane = t & 63;    // = b - bc
  const float4* wp4 = (const float4*)Wt + ci * 4096 + w * 4;
  float acc[16];
#pragma unroll
  for (int q = 0; q < 16; ++q) acc[q] = 0.f;

#pragma unroll 4
  for (int m = 0; m < 128; ++m) {
    float xv = xs[m * 64 + lane];
#pragma unroll
    for (int q = 0; q < 4; ++q) {
      float4 wv = wp4[m * 32 + q];
      acc[q * 4 + 0] = fmaf(xv, wv.x, acc[q * 4 + 0]);
      acc[q * 4 + 1] = fmaf(xv, wv.y, acc[q * 4 + 1]);
      acc[q * 4 + 2] = fmaf(xv, wv.z, acc[q * 4 + 2]);
      acc[q * 4 + 3] = fmaf(xv, wv.w, acc[q * 4 + 3]);
    }
  }
  if (i == 0) {
#pragma unroll
    for (int q = 0; q < 16; ++q) acc[q] += blin[w * 16 + q];
  }
#pragma unroll
  for (int q = 0; q < 16; ++q)
    xrT[(w * 16 + q) * 16384 + i * 256 + bc + lane] = acc[q];
}

// ---------------------------------------------------------------------------
// Kernel 3 (product): fused gating + geometric product.
// Block = (n, bc), 4 waves = 4 j-windows, sharing one LDS-staged copy of the
// xT / xrT slices. ALL LDS goes through one explicitly-carved 32 KB union:
//   phase 1 (staging):  xs = smem[0:4096]   rs = smem[4096:8192]
//   phase 2 (output):   ot_w = smem[w*1088 : w*1088+1088]  (max 4347 < 8192)
// R4's bug: ot was carved from a 4096-float array and wave 3 ran 256 floats
// past its end -> garbage in j=48..63 output. Now bounds hold by construction.
// ---------------------------------------------------------------------------
template <int JW>
__device__ __forceinline__ void prod_body(
    const float* __restrict__ xv, const float* __restrict__ rv,
    const float* __restrict__ gl, float* __restrict__ out,
    float* __restrict__ ot, int n, int bc, int lane) {
  float acc[16];
#pragma unroll
  for (int jj = 0; jj < 16; ++jj) acc[jj] = 0.f;
#pragma unroll
  for (int k = 0; k < 64; ++k) {
#pragma unroll
    for (int jj = 0; jj < 16; ++jj) {
      const int j = JW * 16 + jj;
      const int ii = alg::T.itab[j][k];
      const int tt = alg::T.ct[j][k];
      float t = xv[ii] * rv[k];
      acc[jj] = fmaf(alg::T.sgn[j][k] > 0 ? gl[tt] : -gl[tt], t, acc[jj]);
    }
  }
  // transpose 16x64 tile through wave-private LDS region (wave-synchronous)
#pragma unroll
  for (int jj = 0; jj < 16; ++jj) ot[jj * 68 + lane] = acc[jj];
  __builtin_amdgcn_s_waitcnt(0);  // lgkmcnt(0)
#pragma unroll
  for (int p = 0; p < 16; ++p) {
    int j = lane & 15, br = p * 4 + (lane >> 4);
    out[(bc + br) * 8192 + n * 64 + JW * 16 + j] = ot[j * 68 + br];
  }
}

__global__ __launch_bounds__(256, 2) void kprod(
    const float* __restrict__ xT, const float* __restrict__ xr,
    const float* __restrict__ g, const float* __restrict__ an,
    float* __restrict__ out) {
  __shared__ float smem[8192];   // 32 KB explicit union
  float* xs = smem;              // [i][b] 16 KB (staging phase)
  float* rs = smem + 4096;       // [i][b] 16 KB (staging phase)
  int bid = blockIdx.x;          // 512 blocks: (n in 0..127) x (bc in 0..3)
  int n = bid >> 2;
  int bc = (bid & 3) << 6;
  int t = threadIdx.x;
  int w = t >> 6;                // wave -> j-window
  int lane = t & 63;             // = b - bc

  // ---- cooperative staging: read each slice from global exactly once ----
  {
    int b = t & 63, i0 = t >> 6;  // i0 in 0..3
    const float* sx = xT + n * 256 + bc + b;
    const float* sr = xr + n * 16384 + bc + b;
#pragma unroll
    for (int r = 0; r < 16; ++r) {
      int i = i0 * 16 + r;
      xs[i * 64 + b] = sx[i * 32768];
      rs[i * 64 + b] = sr[i * 256];
    }
  }
  __syncthreads();

  // ---- per-wave register copies ----
  float xv[64], rv[64];
#pragma unroll
  for (int i = 0; i < 64; ++i) xv[i] = xs[i * 64 + lane];
#pragma unroll
  for (int i = 0; i < 64; ++i) rv[i] = rs[i * 64 + lane];

  float gl[64];
#pragma unroll
  for (int q = 0; q < 64; ++q) gl[q] = rfl(g[n * 64 + q]);

  // ---- gating (per lane = per b) ----
  float s[4] = {0.f, 0.f, 0.f, 0.f};
#pragma unroll
  for (int i = 0; i < 64; ++i) {
    const int c = alg::T.cls[i];
    s[c] = fmaf(rv[i], rv[i], s[c]);
  }
  float r[4];
#pragma unroll
  for (int c = 0; c < 4; ++c) {
    float a = rfl(an[n * 4 + c]);
    float sig = 1.f / (1.f + __expf(-a));
    float gate = sig * (sqrtf(s[c]) - 1.f) + 1.f;
    r[c] = 1.f / (gate + 1e-6f);
  }
#pragma unroll
  for (int i = 0; i < 64; ++i) rv[i] *= r[alg::T.cls[i]];

  __syncthreads();  // staging data now dead; re-carve smem as output scratch
  float* ot = smem + w * 1088;   // 4 x 1088 = 4352 floats <= 8192, in-bounds

  switch (w) {
    case 0: prod_body<0>(xv, rv, gl, out, ot, n, bc, lane); break;
    case 1: prod_body<1>(xv, rv, gl, out, ot, n, bc, lane); break;
    case 2: prod_body<2>(xv, rv, gl, out, ot, n, bc, lane); break;
    case 3: prod_body<3>(xv, rv, gl, out, ot, n, bc, lane); break;
  }
}

// ---------------------------------------------------------------------------
extern "C" void kernel_launch(void* const* d_in, const int* in_sizes, int n_in,
                              void* d_out, int out_size, void* d_ws, size_t ws_size,
                              hipStream_t stream) {
  (void)n_in; (void)out_size; (void)ws_size;
  const float* x    = (const float*)d_in[0];
  const float* wgp  = (const float*)d_in[1];
  const float* wlin = (const float*)d_in[2];
  const float* blin = (const float*)d_in[3];
  const float* an   = (const float*)d_in[4];
  const int*   pidx = (const int*)d_in[7];
  int P = in_sizes[7] / 3;

  float* ws  = (float*)d_ws;
  float* xT  = ws;                // 2,097,152 floats (8 MB)
  float* xrT = ws + 2097152;      // 2,097,152 floats (8 MB)
  float* Wt  = ws + 4194304;      // 65,536 floats (256 KB)
  float* g   = ws + 4259840;      // 8,192 floats (32 KB)

  kprep<<<800, 256, 0, stream>>>(x, wlin, wgp, pidx, P, xT, Wt, g);
  klin<<<256, 512, 0, stream>>>(xT, Wt, blin, xrT);
  kprod<<<512, 256, 0, stream>>>(xT, xrT, g, an, (float*)d_out);
}

// Round 6
// 111.430 us; speedup vs baseline: 1.1596x; 1.1596x over previous
//
#include <hip/hip_runtime.h>
#include <hip/hip_bf16.h>

// ---------------------------------------------------------------------------
// Compile-time Clifford algebra tables (N_GEN=6, DIM=64), replicating the
// reference _build_algebra() exactly: blades sorted by (popcount, value).
// ---------------------------------------------------------------------------
namespace alg {
constexpr int pc(int v) { int c = 0; while (v) { c += v & 1; v >>= 1; } return c; }
constexpr int swap_sign_i(int a, int b) {
  int s = 0; a >>= 1;
  while (a) { s += pc(a & b); a >>= 1; }
  return (s & 1) ? -1 : 1;
}
struct Tables {
  int blade[64]; int index[64]; int cls[64];
  int itab[64][64]; int sgn[64][64]; int ct[64][64];
  constexpr Tables() : blade{}, index{}, cls{}, itab{}, sgn{}, ct{} {
    int pos = 0;
    for (int g = 0; g <= 6; ++g)
      for (int b = 0; b < 64; ++b)
        if (pc(b) == g) { blade[pos] = b; index[b] = pos; ++pos; }
    for (int i = 0; i < 64; ++i) cls[i] = pc(blade[i]) & 3;
    for (int J = 0; J < 64; ++J)
      for (int K = 0; K < 64; ++K) {
        int bj = blade[J], bk = blade[K], bi = bj ^ bk;
        int I = index[bi];
        itab[J][K] = I;
        sgn[J][K] = swap_sign_i(bi, bk);
        ct[J][K] = cls[I] * 16 + cls[J] * 4 + cls[K];
      }
  }
};
constexpr Tables T{};
}  // namespace alg

__device__ __forceinline__ float rfl(float v) {
  return __uint_as_float(__builtin_amdgcn_readfirstlane(__float_as_uint(v)));
}

// ---------------------------------------------------------------------------
// Kernel 1 (prep): blocks 0..511  : transpose x[b][m][i] -> xT[i][m][b]
//                  blocks 512..767: Wt[c][m][n] = w_lin[n][m][c]
//                  blocks 768..799: g[n][ci*16+cj*4+ck] from w_gp/path_idx
// ---------------------------------------------------------------------------
__global__ __launch_bounds__(256) void kprep(
    const float* __restrict__ x, const float* __restrict__ wlin,
    const float* __restrict__ wgp, const int* __restrict__ pidx, int P,
    float* __restrict__ xT, float* __restrict__ Wt, float* __restrict__ g) {
  int bid = blockIdx.x;
  if (bid < 512) {
    __shared__ float tile[64 * 65];
    int m = bid >> 2, bc = (bid & 3) << 6;
    int lane = threadIdx.x & 63, row = threadIdx.x >> 6;
#pragma unroll
    for (int p = 0; p < 16; ++p) {
      int b = p * 4 + row;
      tile[lane * 65 + b] = x[(bc + b) * 8192 + m * 64 + lane];
    }
    __syncthreads();
#pragma unroll
    for (int p = 0; p < 16; ++p) {
      int il = p * 4 + row;
      xT[il * 32768 + m * 256 + bc + lane] = tile[il * 65 + lane];
    }
  } else if (bid < 768) {
    int id = (bid - 512) * 256 + threadIdx.x;  // 0..65535
    int n = id & 127, m = (id >> 7) & 127, c = id >> 14;
    Wt[c * 16384 + m * 128 + n] = wlin[n * 512 + m * 4 + c];
  } else {
    int id = (bid - 768) * 256 + threadIdx.x;  // 0..8191
    int n = id >> 6, t = id & 63;
    int ti = t >> 4, tj = (t >> 2) & 3, tk = t & 3;
    float v = 0.f;
    for (int p = 0; p < P; ++p)
      if (pidx[p * 3] == ti && pidx[p * 3 + 1] == tj && pidx[p * 3 + 2] == tk)
        v = wgp[n * P + p];
    g[n * 64 + t] = v;
  }
}

// ---------------------------------------------------------------------------
// Kernel 2 (linear): xr[b,n,i] = sum_m x[b,m,i]*Wt[cls_i][m][n]  (+b_lin at i=0)
// Block = (i, bc), 512 threads = 8 waves; x-slice staged in LDS once.
// KEY (R6): wave id via readfirstlane -> weight addresses provably
// wave-uniform -> compiler emits scalar (s_load) weight broadcasts instead of
// per-lane VMEM broadcast loads (R2 had this property, R4/R5 lost it).
// ---------------------------------------------------------------------------
__global__ __launch_bounds__(512) void klin(
    const float* __restrict__ xT, const float* __restrict__ Wt,
    const float* __restrict__ blin, float* __restrict__ xrT) {
  __shared__ float xs[128 * 64];  // [m][b], 32 KB
  int bid = blockIdx.x;           // 256 blocks: (i in 0..63) x (bc in 0..3)
  int i = bid >> 2;
  int bc = (bid & 3) << 6;
  int ci = alg::T.cls[i];
  int t = threadIdx.x;
  {
    int b = t & 63, m0 = t >> 6;  // m0 in 0..7
    const float* src = xT + i * 32768 + bc + b;
#pragma unroll
    for (int r = 0; r < 16; ++r) {
      int m = m0 * 16 + r;
      xs[m * 64 + b] = src[m * 256];
    }
  }
  __syncthreads();

  int w = __builtin_amdgcn_readfirstlane(t >> 6);  // uniform wave id 0..7
  int lane = t & 63;                               // = b - bc
  const float4* wp4 = (const float4*)Wt + ci * 4096 + w * 4;
  float acc[16];
#pragma unroll
  for (int q = 0; q < 16; ++q) acc[q] = 0.f;

#pragma unroll 4
  for (int m = 0; m < 128; ++m) {
    float xv = xs[m * 64 + lane];
#pragma unroll
    for (int q = 0; q < 4; ++q) {
      float4 wv = wp4[m * 32 + q];
      acc[q * 4 + 0] = fmaf(xv, wv.x, acc[q * 4 + 0]);
      acc[q * 4 + 1] = fmaf(xv, wv.y, acc[q * 4 + 1]);
      acc[q * 4 + 2] = fmaf(xv, wv.z, acc[q * 4 + 2]);
      acc[q * 4 + 3] = fmaf(xv, wv.w, acc[q * 4 + 3]);
    }
  }
  if (i == 0) {
#pragma unroll
    for (int q = 0; q < 16; ++q) acc[q] += blin[w * 16 + q];
  }
#pragma unroll
  for (int q = 0; q < 16; ++q)
    xrT[(w * 16 + q) * 16384 + i * 256 + bc + lane] = acc[q];
}

// ---------------------------------------------------------------------------
// Kernel 3 (product): fused gating + geometric product.
// Block = (n, bc), 4 waves = 4 j-windows sharing one LDS-staged slice copy.
// LDS is one explicit 32 KB union: staging [0:8192), then re-carved as 4
// wave-private 1088-float output tiles (max idx 4351 < 8192, in-bounds).
// Wave id via readfirstlane -> uniform switch, scalar branch.
// ---------------------------------------------------------------------------
template <int JW>
__device__ __forceinline__ void prod_body(
    const float* __restrict__ xv, const float* __restrict__ rv,
    const float* __restrict__ gl, float* __restrict__ out,
    float* __restrict__ ot, int n, int bc, int lane) {
  float acc[16];
#pragma unroll
  for (int jj = 0; jj < 16; ++jj) acc[jj] = 0.f;
#pragma unroll
  for (int k = 0; k < 64; ++k) {
#pragma unroll
    for (int jj = 0; jj < 16; ++jj) {
      const int j = JW * 16 + jj;
      const int ii = alg::T.itab[j][k];
      const int tt = alg::T.ct[j][k];
      float t = xv[ii] * rv[k];
      acc[jj] = fmaf(alg::T.sgn[j][k] > 0 ? gl[tt] : -gl[tt], t, acc[jj]);
    }
  }
  // transpose 16x64 tile through wave-private LDS region (wave-synchronous)
#pragma unroll
  for (int jj = 0; jj < 16; ++jj) ot[jj * 68 + lane] = acc[jj];
  __builtin_amdgcn_s_waitcnt(0);  // lgkmcnt(0)
#pragma unroll
  for (int p = 0; p < 16; ++p) {
    int j = lane & 15, br = p * 4 + (lane >> 4);
    out[(bc + br) * 8192 + n * 64 + JW * 16 + j] = ot[j * 68 + br];
  }
}

__global__ __launch_bounds__(256, 2) void kprod(
    const float* __restrict__ xT, const float* __restrict__ xr,
    const float* __restrict__ g, const float* __restrict__ an,
    float* __restrict__ out) {
  __shared__ float smem[8192];   // 32 KB explicit union
  float* xs = smem;              // [i][b] 16 KB (staging phase)
  float* rs = smem + 4096;       // [i][b] 16 KB (staging phase)
  int bid = blockIdx.x;          // 512 blocks: (n in 0..127) x (bc in 0..3)
  int n = bid >> 2;
  int bc = (bid & 3) << 6;
  int t = threadIdx.x;
  int w = __builtin_amdgcn_readfirstlane(t >> 6);  // uniform wave id
  int lane = t & 63;                               // = b - bc

  // ---- cooperative staging: read each slice from global exactly once ----
  {
    int b = t & 63, i0 = t >> 6;  // i0 in 0..3
    const float* sx = xT + n * 256 + bc + b;
    const float* sr = xr + n * 16384 + bc + b;
#pragma unroll
    for (int r = 0; r < 16; ++r) {
      int i = i0 * 16 + r;
      xs[i * 64 + b] = sx[i * 32768];
      rs[i * 64 + b] = sr[i * 256];
    }
  }
  __syncthreads();

  // ---- per-wave register copies ----
  float xv[64], rv[64];
#pragma unroll
  for (int i = 0; i < 64; ++i) xv[i] = xs[i * 64 + lane];
#pragma unroll
  for (int i = 0; i < 64; ++i) rv[i] = rs[i * 64 + lane];

  float gl[64];
#pragma unroll
  for (int q = 0; q < 64; ++q) gl[q] = rfl(g[n * 64 + q]);

  // ---- gating (per lane = per b) ----
  float s[4] = {0.f, 0.f, 0.f, 0.f};
#pragma unroll
  for (int i = 0; i < 64; ++i) {
    const int c = alg::T.cls[i];
    s[c] = fmaf(rv[i], rv[i], s[c]);
  }
  float r[4];
#pragma unroll
  for (int c = 0; c < 4; ++c) {
    float a = rfl(an[n * 4 + c]);
    float sig = 1.f / (1.f + __expf(-a));
    float gate = sig * (sqrtf(s[c]) - 1.f) + 1.f;
    r[c] = 1.f / (gate + 1e-6f);
  }
#pragma unroll
  for (int i = 0; i < 64; ++i) rv[i] *= r[alg::T.cls[i]];

  __syncthreads();  // staging data now dead; re-carve smem as output scratch
  float* ot = smem + w * 1088;   // 4 x 1088 = 4352 floats <= 8192, in-bounds

  switch (w) {
    case 0: prod_body<0>(xv, rv, gl, out, ot, n, bc, lane); break;
    case 1: prod_body<1>(xv, rv, gl, out, ot, n, bc, lane); break;
    case 2: prod_body<2>(xv, rv, gl, out, ot, n, bc, lane); break;
    case 3: prod_body<3>(xv, rv, gl, out, ot, n, bc, lane); break;
  }
}

// ---------------------------------------------------------------------------
extern "C" void kernel_launch(void* const* d_in, const int* in_sizes, int n_in,
                              void* d_out, int out_size, void* d_ws, size_t ws_size,
                              hipStream_t stream) {
  (void)n_in; (void)out_size; (void)ws_size;
  const float* x    = (const float*)d_in[0];
  const float* wgp  = (const float*)d_in[1];
  const float* wlin = (const float*)d_in[2];
  const float* blin = (const float*)d_in[3];
  const float* an   = (const float*)d_in[4];
  const int*   pidx = (const int*)d_in[7];
  int P = in_sizes[7] / 3;

  float* ws  = (float*)d_ws;
  float* xT  = ws;                // 2,097,152 floats (8 MB)
  float* xrT = ws + 2097152;      // 2,097,152 floats (8 MB)
  float* Wt  = ws + 4194304;      // 65,536 floats (256 KB)
  float* g   = ws + 4259840;      // 8,192 floats (32 KB)

  kprep<<<800, 256, 0, stream>>>(x, wlin, wgp, pidx, P, xT, Wt, g);
  klin<<<256, 512, 0, stream>>>(xT, Wt, blin, xrT);
  kprod<<<512, 256, 0, stream>>>(xT, xrT, g, an, (float*)d_out);
}

// Round 8
// 111.315 us; speedup vs baseline: 1.1607x; 1.0010x over previous
//
#include <hip/hip_runtime.h>
#include <hip/hip_bf16.h>

// ---------------------------------------------------------------------------
// Compile-time Clifford algebra tables (N_GEN=6, DIM=64), replicating the
// reference _build_algebra() exactly: blades sorted by (popcount, value).
// ---------------------------------------------------------------------------
namespace alg {
constexpr int pc(int v) { int c = 0; while (v) { c += v & 1; v >>= 1; } return c; }
constexpr int swap_sign_i(int a, int b) {
  int s = 0; a >>= 1;
  while (a) { s += pc(a & b); a >>= 1; }
  return (s & 1) ? -1 : 1;
}
struct Tables {
  int blade[64]; int index[64]; int cls[64];
  int itab[64][64]; int sgn[64][64]; int ct[64][64];
  constexpr Tables() : blade{}, index{}, cls{}, itab{}, sgn{}, ct{} {
    int pos = 0;
    for (int g = 0; g <= 6; ++g)
      for (int b = 0; b < 64; ++b)
        if (pc(b) == g) { blade[pos] = b; index[b] = pos; ++pos; }
    for (int i = 0; i < 64; ++i) cls[i] = pc(blade[i]) & 3;
    for (int J = 0; J < 64; ++J)
      for (int K = 0; K < 64; ++K) {
        int bj = blade[J], bk = blade[K], bi = bj ^ bk;
        int I = index[bi];
        itab[J][K] = I;
        sgn[J][K] = swap_sign_i(bi, bk);
        ct[J][K] = cls[I] * 16 + cls[J] * 4 + cls[K];
      }
  }
};
constexpr Tables T{};
}  // namespace alg

__device__ __forceinline__ float rfl(float v) {
  return __uint_as_float(__builtin_amdgcn_readfirstlane(__float_as_uint(v)));
}

// ---------------------------------------------------------------------------
// Kernel 1 (prep): blocks 0..511  : transpose x[b][m][i] -> xT[i][m][b]
//                  blocks 512..767: Wt[c][m][n] = w_lin[n][m][c]
//                  blocks 768..799: g[n][ci*16+cj*4+ck] from w_gp/path_idx
// ---------------------------------------------------------------------------
__global__ __launch_bounds__(256) void kprep(
    const float* __restrict__ x, const float* __restrict__ wlin,
    const float* __restrict__ wgp, const int* __restrict__ pidx, int P,
    float* __restrict__ xT, float* __restrict__ Wt, float* __restrict__ g) {
  int bid = blockIdx.x;
  if (bid < 512) {
    __shared__ float tile[64 * 65];
    int m = bid >> 2, bc = (bid & 3) << 6;
    int lane = threadIdx.x & 63, row = threadIdx.x >> 6;
#pragma unroll
    for (int p = 0; p < 16; ++p) {
      int b = p * 4 + row;
      tile[lane * 65 + b] = x[(bc + b) * 8192 + m * 64 + lane];
    }
    __syncthreads();
#pragma unroll
    for (int p = 0; p < 16; ++p) {
      int il = p * 4 + row;
      xT[il * 32768 + m * 256 + bc + lane] = tile[il * 65 + lane];
    }
  } else if (bid < 768) {
    int id = (bid - 512) * 256 + threadIdx.x;  // 0..65535
    int n = id & 127, m = (id >> 7) & 127, c = id >> 14;
    Wt[c * 16384 + m * 128 + n] = wlin[n * 512 + m * 4 + c];
  } else {
    int id = (bid - 768) * 256 + threadIdx.x;  // 0..8191
    int n = id >> 6, t = id & 63;
    int ti = t >> 4, tj = (t >> 2) & 3, tk = t & 3;
    float v = 0.f;
    for (int p = 0; p < P; ++p)
      if (pidx[p * 3] == ti && pidx[p * 3 + 1] == tj && pidx[p * 3 + 2] == tk)
        v = wgp[n * P + p];
    g[n * 64 + t] = v;
  }
}

// ---------------------------------------------------------------------------
// Kernel 2 (linear): xr[b,n,i] = sum_m x[b,m,i]*Wt[cls_i][m][n]  (+b_lin at i=0)
// Block = (i, bc), 512 threads = 8 waves; x-slice staged in LDS once.
// Wave id via readfirstlane -> weight addresses provably wave-uniform ->
// scalar (s_load) weight broadcasts (the R5 regression was losing this).
// ---------------------------------------------------------------------------
__global__ __launch_bounds__(512) void klin(
    const float* __restrict__ xT, const float* __restrict__ Wt,
    const float* __restrict__ blin, float* __restrict__ xrT) {
  __shared__ float xs[128 * 64];  // [m][b], 32 KB
  int bid = blockIdx.x;           // 256 blocks: (i in 0..63) x (bc in 0..3)
  int i = bid >> 2;
  int bc = (bid & 3) << 6;
  int ci = alg::T.cls[i];
  int t = threadIdx.x;
  {
    int b = t & 63, m0 = t >> 6;  // m0 in 0..7
    const float* src = xT + i * 32768 + bc + b;
#pragma unroll
    for (int r = 0; r < 16; ++r) {
      int m = m0 * 16 + r;
      xs[m * 64 + b] = src[m * 256];
    }
  }
  __syncthreads();

  int w = __builtin_amdgcn_readfirstlane(t >> 6);  // uniform wave id 0..7
  int lane = t & 63;                               // = b - bc
  const float4* wp4 = (const float4*)Wt + ci * 4096 + w * 4;
  float acc[16];
#pragma unroll
  for (int q = 0; q < 16; ++q) acc[q] = 0.f;

#pragma unroll 4
  for (int m = 0; m < 128; ++m) {
    float xv = xs[m * 64 + lane];
#pragma unroll
    for (int q = 0; q < 4; ++q) {
      float4 wv = wp4[m * 32 + q];
      acc[q * 4 + 0] = fmaf(xv, wv.x, acc[q * 4 + 0]);
      acc[q * 4 + 1] = fmaf(xv, wv.y, acc[q * 4 + 1]);
      acc[q * 4 + 2] = fmaf(xv, wv.z, acc[q * 4 + 2]);
      acc[q * 4 + 3] = fmaf(xv, wv.w, acc[q * 4 + 3]);
    }
  }
  if (i == 0) {
#pragma unroll
    for (int q = 0; q < 16; ++q) acc[q] += blin[w * 16 + q];
  }
#pragma unroll
  for (int q = 0; q < 16; ++q)
    xrT[(w * 16 + q) * 16384 + i * 256 + bc + lane] = acc[q];
}

// ---------------------------------------------------------------------------
// Kernel 3 (product): fused gating + geometric product.
// Block = (n, bc), 4 waves = 4 j-windows sharing one LDS-staged slice copy.
// LDS is one explicit 32 KB union: staging [0:8192), then re-carved as 4
// wave-private 1088-float output tiles (max idx 4351 < 8192, in-bounds).
// ---------------------------------------------------------------------------
template <int JW>
__device__ __forceinline__ void prod_body(
    const float* __restrict__ xv, const float* __restrict__ rv,
    const float* __restrict__ gl, float* __restrict__ out,
    float* __restrict__ ot, int n, int bc, int lane) {
  float acc[16];
#pragma unroll
  for (int jj = 0; jj < 16; ++jj) acc[jj] = 0.f;
#pragma unroll
  for (int k = 0; k < 64; ++k) {
#pragma unroll
    for (int jj = 0; jj < 16; ++jj) {
      const int j = JW * 16 + jj;
      const int ii = alg::T.itab[j][k];
      const int tt = alg::T.ct[j][k];
      float t = xv[ii] * rv[k];
      acc[jj] = fmaf(alg::T.sgn[j][k] > 0 ? gl[tt] : -gl[tt], t, acc[jj]);
    }
  }
  // transpose 16x64 tile through wave-private LDS region (wave-synchronous)
#pragma unroll
  for (int jj = 0; jj < 16; ++jj) ot[jj * 68 + lane] = acc[jj];
  __builtin_amdgcn_s_waitcnt(0);  // lgkmcnt(0)
#pragma unroll
  for (int p = 0; p < 16; ++p) {
    int j = lane & 15, br = p * 4 + (lane >> 4);
    out[(bc + br) * 8192 + n * 64 + JW * 16 + j] = ot[j * 68 + br];
  }
}

__global__ __launch_bounds__(256, 2) void kprod(
    const float* __restrict__ xT, const float* __restrict__ xr,
    const float* __restrict__ g, const float* __restrict__ an,
    float* __restrict__ out) {
  __shared__ float smem[8192];   // 32 KB explicit union
  float* xs = smem;              // [i][b] 16 KB (staging phase)
  float* rs = smem + 4096;       // [i][b] 16 KB (staging phase)
  int bid = blockIdx.x;          // 512 blocks: (n in 0..127) x (bc in 0..3)
  int n = bid >> 2;
  int bc = (bid & 3) << 6;
  int t = threadIdx.x;
  int w = __builtin_amdgcn_readfirstlane(t >> 6);  // uniform wave id
  int lane = t & 63;                               // = b - bc

  // ---- cooperative staging: read each slice from global exactly once ----
  {
    int b = t & 63, i0 = t >> 6;  // i0 in 0..3
    const float* sx = xT + n * 256 + bc + b;
    const float* sr = xr + n * 16384 + bc + b;
#pragma unroll
    for (int r = 0; r < 16; ++r) {
      int i = i0 * 16 + r;
      xs[i * 64 + b] = sx[i * 32768];
      rs[i * 64 + b] = sr[i * 256];
    }
  }
  __syncthreads();

  // ---- per-wave register copies ----
  float xv[64], rv[64];
#pragma unroll
  for (int i = 0; i < 64; ++i) xv[i] = xs[i * 64 + lane];
#pragma unroll
  for (int i = 0; i < 64; ++i) rv[i] = rs[i * 64 + lane];

  float gl[64];
#pragma unroll
  for (int q = 0; q < 64; ++q) gl[q] = rfl(g[n * 64 + q]);

  // ---- gating (per lane = per b) ----
  float s[4] = {0.f, 0.f, 0.f, 0.f};
#pragma unroll
  for (int i = 0; i < 64; ++i) {
    const int c = alg::T.cls[i];
    s[c] = fmaf(rv[i], rv[i], s[c]);
  }
  float r[4];
#pragma unroll
  for (int c = 0; c < 4; ++c) {
    float a = rfl(an[n * 4 + c]);
    float sig = 1.f / (1.f + __expf(-a));
    float gate = sig * (sqrtf(s[c]) - 1.f) + 1.f;
    r[c] = 1.f / (gate + 1e-6f);
  }
#pragma unroll
  for (int i = 0; i < 64; ++i) rv[i] *= r[alg::T.cls[i]];

  __syncthreads();  // staging data now dead; re-carve smem as output scratch
  float* ot = smem + w * 1088;   // 4 x 1088 = 4352 floats <= 8192, in-bounds

  switch (w) {
    case 0: prod_body<0>(xv, rv, gl, out, ot, n, bc, lane); break;
    case 1: prod_body<1>(xv, rv, gl, out, ot, n, bc, lane); break;
    case 2: prod_body<2>(xv, rv, gl, out, ot, n, bc, lane); break;
    case 3: prod_body<3>(xv, rv, gl, out, ot, n, bc, lane); break;
  }
}

// ---------------------------------------------------------------------------
extern "C" void kernel_launch(void* const* d_in, const int* in_sizes, int n_in,
                              void* d_out, int out_size, void* d_ws, size_t ws_size,
                              hipStream_t stream) {
  (void)n_in; (void)out_size; (void)ws_size;
  const float* x    = (const float*)d_in[0];
  const float* wgp  = (const float*)d_in[1];
  const float* wlin = (const float*)d_in[2];
  const float* blin = (const float*)d_in[3];
  const float* an   = (const float*)d_in[4];
  const int*   pidx = (const int*)d_in[7];
  int P = in_sizes[7] / 3;

  float* ws  = (float*)d_ws;
  float* xT  = ws;                // 2,097,152 floats (8 MB)
  float* xrT = ws + 2097152;      // 2,097,152 floats (8 MB)
  float* Wt  = ws + 4194304;      // 65,536 floats (256 KB)
  float* g   = ws + 4259840;      // 8,192 floats (32 KB)

  kprep<<<800, 256, 0, stream>>>(x, wlin, wgp, pidx, P, xT, Wt, g);
  klin<<<256, 512, 0, stream>>>(xT, Wt, blin, xrT);
  kprod<<<512, 256, 0, stream>>>(xT, xrT, g, an, (float*)d_out);
}